// Round 5
// baseline (536.545 us; speedup 1.0000x reference)
//
#include <hip/hip_runtime.h>
#include <hip/hip_cooperative_groups.h>

namespace cg = cooperative_groups;

// GraphSAGE 3-layer, N=10000, E=640000, D=128->128->64, MI355X.
// R5: ONE cooperative persistent-block kernel (was 6 dispatches). R4 accounting
// showed ~4us per dispatch boundary (~18us total) vs ~1-2us per grid barrier.
// Phase bodies are bit-identical to R4 (absmax must stay 0.015625):
//  ph0 hist + bf16 prep (x->bf16, W->W^T bf16)      [320 items]
//  ph1 scatter w/ inline redundant scan              [250]
//  ph2 per-bin fine sort + MFMA dense0               [626]
//  ph3 agg L0 + relu + MFMA dense1 (LDS-fused)       [625]
//  ph4 agg L1 + relu + MFMA dense2 (LDS-fused)       [625]
//  ph5 agg L2 -> d_out                               [313]
// Aggregation is post-matmul (linearity of mean agg). Neighbor tables bf16,
// fp32 accumulate everywhere; self path hs stays fp32.
// MFMA layouts (verified R4): A[m=lane&15][k=quad*8+j], B[n=lane&15][k=quad*8+j]
// (A·B^T with W^T staged), C/D col=lane&15, row=quad*4+reg.

#define NN 10000
#define NE 640000
#define NBINS 313      // coarse bin = dst >> 5
#define NBLKA 250
#define CHUNK 2560     // 250*2560 == NE
#define SORT_CAP 4096

typedef __attribute__((ext_vector_type(8))) short s8v;   // 8 bf16 (4 VGPRs)
typedef __attribute__((ext_vector_type(4))) float f4v;   // MFMA C/D

__device__ __forceinline__ ushort f2bf(float f) {        // RNE f32->bf16
    unsigned u = __float_as_uint(f);
    return (ushort)((u + 0x7FFFu + ((u >> 16) & 1u)) >> 16);
}
__device__ __forceinline__ unsigned pack2(float a, float b) {
    return (unsigned)f2bf(a) | ((unsigned)f2bf(b) << 16);
}
__device__ __forceinline__ float bf_lo(unsigned u) { return __uint_as_float(u << 16); }
__device__ __forceinline__ float bf_hi(unsigned u) { return __uint_as_float(u & 0xFFFF0000u); }

struct Prm {
    const int *esrc, *edst;
    const float *x, *Ws0, *Wn0, *b0, *Ws1, *Wn1, *b1, *Ws2, *Wn2, *b2;
    float* out;
    float *hsA, *hsB;
    ushort *hnA, *hnB, *xb, *wt;
    unsigned* tmp;
    int *ssrc, *offs, *blockhist, *binstart;
};

// ---------------- ph0 bodies ----------------

__device__ void hist_body(const Prm& p, int blk, int* smem) {
    int* h = smem;                           // NBINS ints
    int tid = threadIdx.x;
    for (int i = tid; i < NBINS; i += 256) h[i] = 0;
    __syncthreads();
    int base = blk * CHUNK;
    for (int i = tid; i < CHUNK; i += 256)
        atomicAdd(&h[p.edst[base + i] >> 5], 1);
    __syncthreads();
    for (int i = tid; i < NBINS; i += 256)
        p.blockhist[blk * NBINS + i] = h[i];
}

__device__ void xconv_body(const Prm& p, int cb) {
    const float4* xv = (const float4*)p.x;
    uint2* xo = (uint2*)p.xb;
    for (int i = threadIdx.x; i < 5000; i += 256) {
        int idx = cb * 5000 + i;
        float4 v = xv[idx];
        xo[idx] = make_uint2(pack2(v.x, v.y), pack2(v.z, v.w));
    }
}

__device__ void wconv_body(const Prm& p, int m) {
    const float* W = (m == 0) ? p.Ws0 : (m == 1) ? p.Wn0 : (m == 2) ? p.Ws1
                   : (m == 3) ? p.Wn1 : (m == 4) ? p.Ws2 : p.Wn2;
    int MC = (m < 4) ? 128 : 64;
    ushort* dst = p.wt + ((m < 4) ? m * 16384 : 65536 + (m - 4) * 8192);
    int tot = 128 * MC;
    for (int idx = threadIdx.x; idx < tot; idx += 256) {
        int k = (MC == 128) ? (idx >> 7) : (idx >> 6);
        int n = (MC == 128) ? (idx & 127) : (idx & 63);
        dst[n * 128 + k] = f2bf(W[idx]);
    }
}

// ---------------- ph1: scatter with inline scan ----------------

__device__ void scatter_body(const Prm& p, int blk, int* smem) {
    int* sa = smem;                          // 512
    int* sb = smem + 512;                    // 512
    int* cur = smem + 1024;                  // NBINS
    int tid = threadIdx.x;
    int bin0 = tid, bin1 = tid + 256;
    int stot0 = 0, smine0 = 0, stot1 = 0, smine1 = 0;
    for (int b = 0; b < NBLKA; ++b) {        // coalesced: consecutive bins/lane
        int v0 = p.blockhist[b * NBINS + bin0];
        int v1 = (bin1 < NBINS) ? p.blockhist[b * NBINS + bin1] : 0;
        stot0 += v0; stot1 += v1;
        if (b < blk) { smine0 += v0; smine1 += v1; }
    }
    sa[bin0] = stot0; sa[bin1] = stot1;
    __syncthreads();
    int* pa = sa; int* pb = sb;
    for (int off = 1; off < 512; off <<= 1) {   // Hillis-Steele, ping-pong
        int x0 = pa[bin0] + ((bin0 >= off) ? pa[bin0 - off] : 0);
        int x1 = pa[bin1] + ((bin1 >= off) ? pa[bin1 - off] : 0);
        pb[bin0] = x0; pb[bin1] = x1;
        __syncthreads();
        int* t = pa; pa = pb; pb = t;
    }
    int bs0 = pa[bin0] - stot0;              // exclusive binstart
    cur[bin0] = bs0 + smine0;
    int bs1 = 0;
    if (bin1 < NBINS) { bs1 = pa[bin1] - stot1; cur[bin1] = bs1 + smine1; }
    if (blk == 0) {
        p.binstart[bin0] = bs0;
        if (bin1 < NBINS) p.binstart[bin1] = bs1;
        if (tid == 0) p.binstart[NBINS] = pa[NBINS - 1];
    }
    __syncthreads();
    int base = blk * CHUNK;
    for (int i = tid; i < CHUNK; i += 256) {
        int d = p.edst[base + i], s = p.esrc[base + i];
        int pos = atomicAdd(&cur[d >> 5], 1);
        p.tmp[pos] = ((unsigned)s << 5) | (unsigned)(d & 31);
    }
}

// ---------------- ph2 bodies ----------------

__device__ void sort_body(const Prm& p, int b, int* smem) {
    int* stage = smem;                       // SORT_CAP
    int* cnt32 = smem + SORT_CAP;            // 32
    int* cur32 = smem + SORT_CAP + 32;       // 32
    int tid = threadIdx.x;
    int beg = p.binstart[b], end = p.binstart[b + 1], cnt = end - beg;
    if (tid < 32) cnt32[tid] = 0;
    __syncthreads();
    for (int i = tid; i < cnt; i += 256)
        atomicAdd(&cnt32[p.tmp[beg + i] & 31], 1);
    __syncthreads();
    if (tid == 0) {
        int run = 0;
        for (int i = 0; i < 32; ++i) {
            int node = b * 32 + i;
            if (node < NN) p.offs[node] = beg + run;
            cur32[i] = run;
            run += cnt32[i];
        }
        if (b == NBINS - 1) p.offs[NN] = end;
    }
    __syncthreads();
    if (cnt <= SORT_CAP) {
        for (int i = tid; i < cnt; i += 256) {
            unsigned q = p.tmp[beg + i];
            int pos = atomicAdd(&cur32[q & 31], 1);
            stage[pos] = (int)(q >> 5);
        }
        __syncthreads();
        for (int i = tid; i < cnt; i += 256)   // coalesced stream-out
            p.ssrc[beg + i] = stage[i];
    } else {                                    // safety fallback
        for (int i = tid; i < cnt; i += 256) {
            unsigned q = p.tmp[beg + i];
            int pos = atomicAdd(&cur32[q & 31], 1);
            p.ssrc[beg + pos] = (int)(q >> 5);
        }
    }
}

__device__ void dense0_body(const Prm& p, int dblk) {
    int l = threadIdx.x & 63, w = threadIdx.x >> 6;
    int mloc = l & 15, quad = l >> 4;
    int row_base = dblk * 32 + (w & 1) * 16;
    int colh = w >> 1;
    int arow = row_base + mloc;
    int arow_c = (arow < NN) ? arow : (NN - 1);
    const ushort* wsT = p.wt;                // Ws0^T
    const ushort* wnT = p.wt + 16384;        // Wn0^T
    f4v accS[4], accN[4];
#pragma unroll
    for (int nt = 0; nt < 4; ++nt) { accS[nt] = (f4v){0,0,0,0}; accN[nt] = (f4v){0,0,0,0}; }
#pragma unroll
    for (int ks = 0; ks < 4; ++ks) {
        int kb = ks * 32 + quad * 8;
        s8v a = *(const s8v*)(p.xb + (size_t)arow_c * 128 + kb);
#pragma unroll
        for (int nt = 0; nt < 4; ++nt) {
            int n = colh * 64 + nt * 16 + mloc;
            s8v bs = *(const s8v*)(wsT + n * 128 + kb);
            s8v bn = *(const s8v*)(wnT + n * 128 + kb);
            accS[nt] = __builtin_amdgcn_mfma_f32_16x16x32_bf16(a, bs, accS[nt], 0, 0, 0);
            accN[nt] = __builtin_amdgcn_mfma_f32_16x16x32_bf16(a, bn, accN[nt], 0, 0, 0);
        }
    }
#pragma unroll
    for (int nt = 0; nt < 4; ++nt) {
        int col = colh * 64 + nt * 16 + mloc;
        float bv = p.b0[col];
#pragma unroll
        for (int r = 0; r < 4; ++r) {
            int row = row_base + quad * 4 + r;
            if (row < NN) {
                p.hsA[(size_t)row * 128 + col] = accS[nt][r] + bv;
                p.hnA[(size_t)row * 128 + col] = f2bf(accN[nt][r]);
            }
        }
    }
}

// ---------------- ph3/ph4: agg + relu + fused MFMA dense ----------------
// item = 16 nodes (625*16 == NN exactly). Gather -> LDS rows -> MFMA.

template <int MOUT>
__device__ void agg_dense_body(const float* __restrict__ hs_in, const ushort* __restrict__ hn_in,
                               const ushort* __restrict__ wsT, const ushort* __restrict__ wnT,
                               const float* __restrict__ bias,
                               float* __restrict__ hs_out, ushort* __restrict__ hn_out,
                               const Prm& p, int item, int* smem) {
    ushort* hrow = (ushort*)smem;            // 16*136 (pad 128->136 vs banks)
    int tid = threadIdx.x;
    int node_loc = tid >> 4, t = tid & 15;
    int node = item * 16 + node_loc;
    int beg = p.offs[node], end = p.offs[node + 1];
    const uint4* hn4 = (const uint4*)hn_in;
    float a0 = 0, a1 = 0, a2 = 0, a3 = 0, a4 = 0, a5 = 0, a6 = 0, a7 = 0;
    int e = beg;
    for (; e + 4 <= end; e += 4) {
        int s0 = p.ssrc[e], s1 = p.ssrc[e + 1], s2 = p.ssrc[e + 2], s3 = p.ssrc[e + 3];
        uint4 v0 = hn4[(size_t)s0 * 16 + t];
        uint4 v1 = hn4[(size_t)s1 * 16 + t];
        uint4 v2 = hn4[(size_t)s2 * 16 + t];
        uint4 v3 = hn4[(size_t)s3 * 16 + t];
        a0 += bf_lo(v0.x) + bf_lo(v1.x) + bf_lo(v2.x) + bf_lo(v3.x);
        a1 += bf_hi(v0.x) + bf_hi(v1.x) + bf_hi(v2.x) + bf_hi(v3.x);
        a2 += bf_lo(v0.y) + bf_lo(v1.y) + bf_lo(v2.y) + bf_lo(v3.y);
        a3 += bf_hi(v0.y) + bf_hi(v1.y) + bf_hi(v2.y) + bf_hi(v3.y);
        a4 += bf_lo(v0.z) + bf_lo(v1.z) + bf_lo(v2.z) + bf_lo(v3.z);
        a5 += bf_hi(v0.z) + bf_hi(v1.z) + bf_hi(v2.z) + bf_hi(v3.z);
        a6 += bf_lo(v0.w) + bf_lo(v1.w) + bf_lo(v2.w) + bf_lo(v3.w);
        a7 += bf_hi(v0.w) + bf_hi(v1.w) + bf_hi(v2.w) + bf_hi(v3.w);
    }
    for (; e < end; ++e) {
        uint4 v = hn4[(size_t)p.ssrc[e] * 16 + t];
        a0 += bf_lo(v.x); a1 += bf_hi(v.x); a2 += bf_lo(v.y); a3 += bf_hi(v.y);
        a4 += bf_lo(v.z); a5 += bf_hi(v.z); a6 += bf_lo(v.w); a7 += bf_hi(v.w);
    }
    int deg = end - beg;
    float sc = 1.0f / (float)(deg > 0 ? deg : 1);
    float4 h4a = ((const float4*)hs_in)[(size_t)node * 32 + 2 * t];
    float4 h4b = ((const float4*)hs_in)[(size_t)node * 32 + 2 * t + 1];
    float r0 = fmaxf(h4a.x + a0 * sc, 0.f), r1 = fmaxf(h4a.y + a1 * sc, 0.f);
    float r2 = fmaxf(h4a.z + a2 * sc, 0.f), r3 = fmaxf(h4a.w + a3 * sc, 0.f);
    float r4 = fmaxf(h4b.x + a4 * sc, 0.f), r5 = fmaxf(h4b.y + a5 * sc, 0.f);
    float r6 = fmaxf(h4b.z + a6 * sc, 0.f), r7 = fmaxf(h4b.w + a7 * sc, 0.f);
    *(uint4*)(hrow + node_loc * 136 + t * 8) =
        make_uint4(pack2(r0, r1), pack2(r2, r3), pack2(r4, r5), pack2(r6, r7));
    __syncthreads();

    // dense: D[16 x MOUT] = H[16x128] @ {Ws|Wn}, fp32 acc
    int l = tid & 63, w = tid >> 6;
    int mloc = l & 15, quad = l >> 4;
    constexpr int NTPW = MOUT / 64;          // n-tiles per wave
    f4v accS[NTPW], accN[NTPW];
#pragma unroll
    for (int nt = 0; nt < NTPW; ++nt) { accS[nt] = (f4v){0,0,0,0}; accN[nt] = (f4v){0,0,0,0}; }
#pragma unroll
    for (int ks = 0; ks < 4; ++ks) {
        int kb = ks * 32 + quad * 8;
        s8v a = *(const s8v*)(hrow + mloc * 136 + kb);
#pragma unroll
        for (int nt = 0; nt < NTPW; ++nt) {
            int n = (w * NTPW + nt) * 16 + mloc;
            s8v bs = *(const s8v*)(wsT + n * 128 + kb);
            s8v bn = *(const s8v*)(wnT + n * 128 + kb);
            accS[nt] = __builtin_amdgcn_mfma_f32_16x16x32_bf16(a, bs, accS[nt], 0, 0, 0);
            accN[nt] = __builtin_amdgcn_mfma_f32_16x16x32_bf16(a, bn, accN[nt], 0, 0, 0);
        }
    }
#pragma unroll
    for (int nt = 0; nt < NTPW; ++nt) {
        int col = (w * NTPW + nt) * 16 + mloc;
        float bv = bias[col];
#pragma unroll
        for (int r = 0; r < 4; ++r) {
            int row = item * 16 + quad * 4 + r;   // always < NN
            hs_out[(size_t)row * MOUT + col] = accS[nt][r] + bv;
            hn_out[(size_t)row * MOUT + col] = f2bf(accN[nt][r]);
        }
    }
}

// ---------------- ph5: final aggregate (M=64) -> d_out ----------------

__device__ void agg_out_body(const Prm& p, int item) {
    int tid = threadIdx.x;
    int node = item * 32 + (tid >> 3);
    int t = tid & 7;
    if (node >= NN) return;                  // no __syncthreads below — safe
    int beg = p.offs[node], end = p.offs[node + 1];
    const uint4* hn4 = (const uint4*)p.hnA;
    float a0 = 0, a1 = 0, a2 = 0, a3 = 0, a4 = 0, a5 = 0, a6 = 0, a7 = 0;
    int e = beg;
    for (; e + 4 <= end; e += 4) {
        int s0 = p.ssrc[e], s1 = p.ssrc[e + 1], s2 = p.ssrc[e + 2], s3 = p.ssrc[e + 3];
        uint4 v0 = hn4[(size_t)s0 * 8 + t];
        uint4 v1 = hn4[(size_t)s1 * 8 + t];
        uint4 v2 = hn4[(size_t)s2 * 8 + t];
        uint4 v3 = hn4[(size_t)s3 * 8 + t];
        a0 += bf_lo(v0.x) + bf_lo(v1.x) + bf_lo(v2.x) + bf_lo(v3.x);
        a1 += bf_hi(v0.x) + bf_hi(v1.x) + bf_hi(v2.x) + bf_hi(v3.x);
        a2 += bf_lo(v0.y) + bf_lo(v1.y) + bf_lo(v2.y) + bf_lo(v3.y);
        a3 += bf_hi(v0.y) + bf_hi(v1.y) + bf_hi(v2.y) + bf_hi(v3.y);
        a4 += bf_lo(v0.z) + bf_lo(v1.z) + bf_lo(v2.z) + bf_lo(v3.z);
        a5 += bf_hi(v0.z) + bf_hi(v1.z) + bf_hi(v2.z) + bf_hi(v3.z);
        a6 += bf_lo(v0.w) + bf_lo(v1.w) + bf_lo(v2.w) + bf_lo(v3.w);
        a7 += bf_hi(v0.w) + bf_hi(v1.w) + bf_hi(v2.w) + bf_hi(v3.w);
    }
    for (; e < end; ++e) {
        uint4 v = hn4[(size_t)p.ssrc[e] * 8 + t];
        a0 += bf_lo(v.x); a1 += bf_hi(v.x); a2 += bf_lo(v.y); a3 += bf_hi(v.y);
        a4 += bf_lo(v.z); a5 += bf_hi(v.z); a6 += bf_lo(v.w); a7 += bf_hi(v.w);
    }
    int deg = end - beg;
    float sc = 1.0f / (float)(deg > 0 ? deg : 1);
    float4 h4a = ((const float4*)p.hsA)[(size_t)node * 16 + 2 * t];
    float4 h4b = ((const float4*)p.hsA)[(size_t)node * 16 + 2 * t + 1];
    ((float4*)p.out)[(size_t)node * 16 + 2 * t] =
        make_float4(h4a.x + a0 * sc, h4a.y + a1 * sc, h4a.z + a2 * sc, h4a.w + a3 * sc);
    ((float4*)p.out)[(size_t)node * 16 + 2 * t + 1] =
        make_float4(h4b.x + a4 * sc, h4b.y + a5 * sc, h4b.z + a6 * sc, h4b.w + a7 * sc);
}

// ---------------- the mega-kernel ----------------

__global__ __launch_bounds__(256, 2) void mega_k(Prm p) {
    __shared__ int smem[SORT_CAP + 64];      // 16.25KB union for all phases
    cg::grid_group grid = cg::this_grid();

    // ph0: hist + bf16 prep
    for (int it = blockIdx.x; it < NBLKA + 64 + 6; it += gridDim.x) {
        if (it < NBLKA) hist_body(p, it, smem);
        else if (it < NBLKA + 64) xconv_body(p, it - NBLKA);
        else wconv_body(p, it - NBLKA - 64);
        __syncthreads();                     // smem reuse across iterations
    }
    grid.sync();

    // ph1: scatter (inline redundant scan of blockhist)
    for (int it = blockIdx.x; it < NBLKA; it += gridDim.x) {
        scatter_body(p, it, smem);
        __syncthreads();
    }
    grid.sync();

    // ph2: fine sort + MFMA dense0
    for (int it = blockIdx.x; it < NBINS + 313; it += gridDim.x) {
        if (it < NBINS) sort_body(p, it, smem);
        else dense0_body(p, it - NBINS);
        __syncthreads();
    }
    grid.sync();

    // ph3: agg L0 + relu + dense1
    for (int it = blockIdx.x; it < NN / 16; it += gridDim.x) {
        agg_dense_body<128>(p.hsA, p.hnA, p.wt + 32768, p.wt + 49152, p.b1,
                            p.hsB, p.hnB, p, it, smem);
        __syncthreads();
    }
    grid.sync();

    // ph4: agg L1 + relu + dense2
    for (int it = blockIdx.x; it < NN / 16; it += gridDim.x) {
        agg_dense_body<64>(p.hsB, p.hnB, p.wt + 65536, p.wt + 73728, p.b2,
                           p.hsA, p.hnA, p, it, smem);
        __syncthreads();
    }
    grid.sync();

    // ph5: agg L2 -> out
    for (int it = blockIdx.x; it < (NN + 31) / 32; it += gridDim.x)
        agg_out_body(p, it);
}

// ---------------- launch ----------------

extern "C" void kernel_launch(void* const* d_in, const int* in_sizes, int n_in,
                              void* d_out, int out_size, void* d_ws, size_t ws_size,
                              hipStream_t stream) {
    Prm p;
    p.x   = (const float*)d_in[0];
    p.Ws0 = (const float*)d_in[1];
    p.Wn0 = (const float*)d_in[2];
    p.b0  = (const float*)d_in[3];
    p.Ws1 = (const float*)d_in[4];
    p.Wn1 = (const float*)d_in[5];
    p.b1  = (const float*)d_in[6];
    p.Ws2 = (const float*)d_in[7];
    p.Wn2 = (const float*)d_in[8];
    p.b2  = (const float*)d_in[9];
    p.esrc = (const int*)d_in[10];
    p.edst = (const int*)d_in[11];
    p.out = (float*)d_out;

    // workspace layout (16B-aligned users first), same as R4
    p.hsA = (float*)d_ws;                              // NN*128 f32
    p.hsB = p.hsA + (size_t)NN * 128;                  // NN*128 f32
    p.hnA = (ushort*)(p.hsB + (size_t)NN * 128);       // NN*128 bf16
    p.hnB = p.hnA + (size_t)NN * 128;                  // NN*128 bf16
    p.xb  = p.hnB + (size_t)NN * 128;                  // NN*128 bf16
    p.wt  = p.xb + (size_t)NN * 128;                   // 81920 bf16 (W^T x6)
    p.tmp = (unsigned*)(p.wt + 81920);                 // NE packed edges
    p.ssrc = (int*)(p.tmp + NE);                       // NE
    p.offs = p.ssrc + NE;                              // NN+1
    p.blockhist = p.offs + NN + 1;                     // NBLKA*NBINS
    p.binstart = p.blockhist + NBLKA * NBINS;          // NBINS+1

    // grid = min(largest phase item count, guaranteed-co-resident capacity)
    int bpc = 0;
    hipError_t e = hipOccupancyMaxActiveBlocksPerMultiprocessor(
        &bpc, reinterpret_cast<const void*>(mega_k), 256, 0);
    if (e != hipSuccess || bpc < 1) bpc = 1;           // conservative fallback
    int grid = bpc * 256;
    if (grid > NBINS + 313) grid = NBINS + 313;        // 626: largest phase

    void* args[] = { &p };
    hipLaunchCooperativeKernel(reinterpret_cast<const void*>(mega_k),
                               dim3(grid), dim3(256), args, 0, stream);
}

// Round 6
// 185.473 us; speedup vs baseline: 2.8928x; 2.8928x over previous
//
#include <hip/hip_runtime.h>

// GraphSAGE 3-layer, N=10000, E=640000, D=128->128->64, MI355X.
// R6: revert R5's cooperative mega-kernel (grid.sync on gfx950 cost ~10x the
// dispatch boundaries it replaced: 504us, all pipes idle). Back to R4's
// 6-dispatch structure with rebalancing:
//  P0 hist + bf16 prep (x->bf16, W->W^T bf16 via LDS transpose) [320 blocks]
//  P1 scatter (inline scan) + MFMA dense0 (independent roles)   [250+313]
//  P2 per-bin fine sort                                         [313]
//  P3 agg L0 + relu + MFMA dense1 (LDS-fused)                   [625]
//  P4 agg L1 + relu + MFMA dense2 (LDS-fused)                   [625]
//  P5 agg L2 -> d_out                                           [313]
// Aggregation is post-matmul (linearity of mean agg). Neighbor tables bf16,
// fp32 accumulate everywhere; self path hs stays fp32.
// MFMA layouts (verified R4): A[m=lane&15][k=quad*8+j], B[n=lane&15][k=quad*8+j]
// (A*B^T with W^T staged), C/D col=lane&15, row=quad*4+reg.

#define NN 10000
#define NE 640000
#define NBINS 313      // coarse bin = dst >> 5
#define NBLKA 250
#define CHUNK 2560     // 250*2560 == NE
#define SORT_CAP 4096

typedef __attribute__((ext_vector_type(8))) short s8v;   // 8 bf16 (4 VGPRs)
typedef __attribute__((ext_vector_type(4))) float f4v;   // MFMA C/D

__device__ __forceinline__ ushort f2bf(float f) {        // RNE f32->bf16
    unsigned u = __float_as_uint(f);
    return (ushort)((u + 0x7FFFu + ((u >> 16) & 1u)) >> 16);
}
__device__ __forceinline__ unsigned pack2(float a, float b) {
    return (unsigned)f2bf(a) | ((unsigned)f2bf(b) << 16);
}
__device__ __forceinline__ float bf_lo(unsigned u) { return __uint_as_float(u << 16); }
__device__ __forceinline__ float bf_hi(unsigned u) { return __uint_as_float(u & 0xFFFF0000u); }

// ---------------- P0: histogram + bf16 prep ----------------

__global__ void prep_k(const int* __restrict__ edst, int* __restrict__ blockhist,
                       const float* __restrict__ x, ushort* __restrict__ xb,
                       const float* __restrict__ Ws0, const float* __restrict__ Wn0,
                       const float* __restrict__ Ws1, const float* __restrict__ Wn1,
                       const float* __restrict__ Ws2, const float* __restrict__ Wn2,
                       ushort* __restrict__ wt) {
    __shared__ ushort ps[128 * 128];         // 32KB: transpose tile / hist union
    int blk = blockIdx.x, tid = threadIdx.x;
    if (blk < NBLKA) {                       // histogram role
        int* h = (int*)ps;
        for (int i = tid; i < NBINS; i += 256) h[i] = 0;
        __syncthreads();
        int base = blk * CHUNK;
        for (int i = tid; i < CHUNK; i += 256)
            atomicAdd(&h[edst[base + i] >> 5], 1);
        __syncthreads();
        for (int i = tid; i < NBINS; i += 256)
            blockhist[blk * NBINS + i] = h[i];
    } else if (blk < NBLKA + 64) {           // x -> bf16 (320000 float4 total)
        int cb = blk - NBLKA;
        const float4* xv = (const float4*)x;
        uint2* xo = (uint2*)xb;
        for (int i = tid; i < 5000; i += 256) {
            int idx = cb * 5000 + i;
            float4 v = xv[idx];
            xo[idx] = make_uint2(pack2(v.x, v.y), pack2(v.z, v.w));
        }
    } else {                                 // 6 weight transposes -> W^T bf16
        int m = blk - NBLKA - 64;            // 0..5
        const float* W = (m == 0) ? Ws0 : (m == 1) ? Wn0 : (m == 2) ? Ws1
                       : (m == 3) ? Wn1 : (m == 4) ? Ws2 : Wn2;
        int MC = (m < 4) ? 128 : 64;
        ushort* dst = wt + ((m < 4) ? m * 16384 : 65536 + (m - 4) * 8192);
        int tot = 128 * MC;
        for (int idx = tid; idx < tot; idx += 256) {     // coalesced read
            int k = (MC == 128) ? (idx >> 7) : (idx >> 6);
            int n = (MC == 128) ? (idx & 127) : (idx & 63);
            ps[n * 128 + k] = f2bf(W[idx]);              // LDS transpose
        }
        __syncthreads();
        for (int idx = tid; idx < tot; idx += 256)       // coalesced write
            dst[idx] = ps[idx];
    }
}

// ---------------- P1: scatter (inline scan) + MFMA dense0 ----------------

__device__ void scatter_body(const int* __restrict__ src, const int* __restrict__ dst,
                             const int* __restrict__ blockhist,
                             int* __restrict__ binstart_g, unsigned* __restrict__ tmp,
                             int blk, int* smem) {
    int* sa = smem;                          // 512
    int* sb = smem + 512;                    // 512
    int* cur = smem + 1024;                  // NBINS
    int tid = threadIdx.x;
    int bin0 = tid, bin1 = tid + 256;
    int stot0 = 0, smine0 = 0, stot1 = 0, smine1 = 0;
    for (int b = 0; b < NBLKA; ++b) {        // coalesced: consecutive bins/lane
        int v0 = blockhist[b * NBINS + bin0];
        int v1 = (bin1 < NBINS) ? blockhist[b * NBINS + bin1] : 0;
        stot0 += v0; stot1 += v1;
        if (b < blk) { smine0 += v0; smine1 += v1; }
    }
    sa[bin0] = stot0; sa[bin1] = stot1;
    __syncthreads();
    int* pa = sa; int* pb = sb;
    for (int off = 1; off < 512; off <<= 1) {   // Hillis-Steele, ping-pong
        int x0 = pa[bin0] + ((bin0 >= off) ? pa[bin0 - off] : 0);
        int x1 = pa[bin1] + ((bin1 >= off) ? pa[bin1 - off] : 0);
        pb[bin0] = x0; pb[bin1] = x1;
        __syncthreads();
        int* t = pa; pa = pb; pb = t;
    }
    int bs0 = pa[bin0] - stot0;              // exclusive binstart
    cur[bin0] = bs0 + smine0;
    int bs1 = 0;
    if (bin1 < NBINS) { bs1 = pa[bin1] - stot1; cur[bin1] = bs1 + smine1; }
    if (blk == 0) {
        binstart_g[bin0] = bs0;
        if (bin1 < NBINS) binstart_g[bin1] = bs1;
        if (tid == 0) binstart_g[NBINS] = pa[NBINS - 1];
    }
    __syncthreads();
    int base = blk * CHUNK;
    for (int i = tid; i < CHUNK; i += 256) {
        int d = dst[base + i], s = src[base + i];
        int pos = atomicAdd(&cur[d >> 5], 1);
        tmp[pos] = ((unsigned)s << 5) | (unsigned)(d & 31);
    }
}

__device__ void dense0_body(const ushort* __restrict__ xb, const ushort* __restrict__ wt,
                            const float* __restrict__ b0,
                            float* __restrict__ hs, ushort* __restrict__ hn, int dblk) {
    int l = threadIdx.x & 63, w = threadIdx.x >> 6;
    int mloc = l & 15, quad = l >> 4;
    int row_base = dblk * 32 + (w & 1) * 16;
    int colh = w >> 1;
    int arow = row_base + mloc;
    int arow_c = (arow < NN) ? arow : (NN - 1);
    const ushort* wsT = wt;                  // Ws0^T
    const ushort* wnT = wt + 16384;          // Wn0^T
    f4v accS[4], accN[4];
#pragma unroll
    for (int nt = 0; nt < 4; ++nt) { accS[nt] = (f4v){0,0,0,0}; accN[nt] = (f4v){0,0,0,0}; }
#pragma unroll
    for (int ks = 0; ks < 4; ++ks) {
        int kb = ks * 32 + quad * 8;
        s8v a = *(const s8v*)(xb + (size_t)arow_c * 128 + kb);
#pragma unroll
        for (int nt = 0; nt < 4; ++nt) {
            int n = colh * 64 + nt * 16 + mloc;
            s8v bs = *(const s8v*)(wsT + n * 128 + kb);
            s8v bn = *(const s8v*)(wnT + n * 128 + kb);
            accS[nt] = __builtin_amdgcn_mfma_f32_16x16x32_bf16(a, bs, accS[nt], 0, 0, 0);
            accN[nt] = __builtin_amdgcn_mfma_f32_16x16x32_bf16(a, bn, accN[nt], 0, 0, 0);
        }
    }
#pragma unroll
    for (int nt = 0; nt < 4; ++nt) {
        int col = colh * 64 + nt * 16 + mloc;
        float bv = b0[col];
#pragma unroll
        for (int r = 0; r < 4; ++r) {
            int row = row_base + quad * 4 + r;
            if (row < NN) {
                hs[(size_t)row * 128 + col] = accS[nt][r] + bv;
                hn[(size_t)row * 128 + col] = f2bf(accN[nt][r]);
            }
        }
    }
}

__global__ void scatdense_k(const int* __restrict__ esrc, const int* __restrict__ edst,
                            const int* __restrict__ blockhist, int* __restrict__ binstart,
                            unsigned* __restrict__ tmp,
                            const ushort* __restrict__ xb, const ushort* __restrict__ wt,
                            const float* __restrict__ b0,
                            float* __restrict__ hs, ushort* __restrict__ hn) {
    __shared__ int smem[1024 + NBINS];
    int blk = blockIdx.x;
    if (blk < NBLKA)
        scatter_body(esrc, edst, blockhist, binstart, tmp, blk, smem);
    else
        dense0_body(xb, wt, b0, hs, hn, blk - NBLKA);
}

// ---------------- P2: per-bin fine sort -> offs[] + ssrc[] ----------------

__global__ void sort_k(const unsigned* __restrict__ tmp, const int* __restrict__ binstart,
                       int* __restrict__ offs, int* __restrict__ ssrc) {
    __shared__ int stage[SORT_CAP];
    __shared__ int cnt32[32];
    __shared__ int cur32[32];
    int b = blockIdx.x, tid = threadIdx.x;
    int beg = binstart[b], end = binstart[b + 1], cnt = end - beg;
    if (tid < 32) cnt32[tid] = 0;
    __syncthreads();
    for (int i = tid; i < cnt; i += 256)
        atomicAdd(&cnt32[tmp[beg + i] & 31], 1);
    __syncthreads();
    if (tid == 0) {
        int run = 0;
        for (int i = 0; i < 32; ++i) {
            int node = b * 32 + i;
            if (node < NN) offs[node] = beg + run;
            cur32[i] = run;
            run += cnt32[i];
        }
        if (b == NBINS - 1) offs[NN] = end;
    }
    __syncthreads();
    if (cnt <= SORT_CAP) {
        for (int i = tid; i < cnt; i += 256) {
            unsigned q = tmp[beg + i];
            int pos = atomicAdd(&cur32[q & 31], 1);
            stage[pos] = (int)(q >> 5);
        }
        __syncthreads();
        for (int i = tid; i < cnt; i += 256)   // coalesced stream-out
            ssrc[beg + i] = stage[i];
    } else {                                    // safety fallback
        for (int i = tid; i < cnt; i += 256) {
            unsigned q = tmp[beg + i];
            int pos = atomicAdd(&cur32[q & 31], 1);
            ssrc[beg + pos] = (int)(q >> 5);
        }
    }
}

// ---------------- P3/P4: agg + relu + fused MFMA dense ----------------
// Block = 16 nodes (625*16 == NN exactly). Gather -> LDS rows -> MFMA.

template <int MOUT>
__global__ void agg_dense_k(const float* __restrict__ hs_in, const ushort* __restrict__ hn_in,
                            const int* __restrict__ offs, const int* __restrict__ ssrc,
                            const ushort* __restrict__ wsT, const ushort* __restrict__ wnT,
                            const float* __restrict__ bias,
                            float* __restrict__ hs_out, ushort* __restrict__ hn_out) {
    __shared__ ushort hrow[16 * 136];        // pad 128->136 vs LDS banks
    int tid = threadIdx.x;
    int node_loc = tid >> 4, t = tid & 15;
    int node = blockIdx.x * 16 + node_loc;
    int beg = offs[node], end = offs[node + 1];
    const uint4* hn4 = (const uint4*)hn_in;
    float a0 = 0, a1 = 0, a2 = 0, a3 = 0, a4 = 0, a5 = 0, a6 = 0, a7 = 0;
    int e = beg;
    for (; e + 4 <= end; e += 4) {
        int s0 = ssrc[e], s1 = ssrc[e + 1], s2 = ssrc[e + 2], s3 = ssrc[e + 3];
        uint4 v0 = hn4[(size_t)s0 * 16 + t];
        uint4 v1 = hn4[(size_t)s1 * 16 + t];
        uint4 v2 = hn4[(size_t)s2 * 16 + t];
        uint4 v3 = hn4[(size_t)s3 * 16 + t];
        a0 += bf_lo(v0.x) + bf_lo(v1.x) + bf_lo(v2.x) + bf_lo(v3.x);
        a1 += bf_hi(v0.x) + bf_hi(v1.x) + bf_hi(v2.x) + bf_hi(v3.x);
        a2 += bf_lo(v0.y) + bf_lo(v1.y) + bf_lo(v2.y) + bf_lo(v3.y);
        a3 += bf_hi(v0.y) + bf_hi(v1.y) + bf_hi(v2.y) + bf_hi(v3.y);
        a4 += bf_lo(v0.z) + bf_lo(v1.z) + bf_lo(v2.z) + bf_lo(v3.z);
        a5 += bf_hi(v0.z) + bf_hi(v1.z) + bf_hi(v2.z) + bf_hi(v3.z);
        a6 += bf_lo(v0.w) + bf_lo(v1.w) + bf_lo(v2.w) + bf_lo(v3.w);
        a7 += bf_hi(v0.w) + bf_hi(v1.w) + bf_hi(v2.w) + bf_hi(v3.w);
    }
    for (; e < end; ++e) {
        uint4 v = hn4[(size_t)ssrc[e] * 16 + t];
        a0 += bf_lo(v.x); a1 += bf_hi(v.x); a2 += bf_lo(v.y); a3 += bf_hi(v.y);
        a4 += bf_lo(v.z); a5 += bf_hi(v.z); a6 += bf_lo(v.w); a7 += bf_hi(v.w);
    }
    int deg = end - beg;
    float sc = 1.0f / (float)(deg > 0 ? deg : 1);
    float4 h4a = ((const float4*)hs_in)[(size_t)node * 32 + 2 * t];
    float4 h4b = ((const float4*)hs_in)[(size_t)node * 32 + 2 * t + 1];
    float r0 = fmaxf(h4a.x + a0 * sc, 0.f), r1 = fmaxf(h4a.y + a1 * sc, 0.f);
    float r2 = fmaxf(h4a.z + a2 * sc, 0.f), r3 = fmaxf(h4a.w + a3 * sc, 0.f);
    float r4 = fmaxf(h4b.x + a4 * sc, 0.f), r5 = fmaxf(h4b.y + a5 * sc, 0.f);
    float r6 = fmaxf(h4b.z + a6 * sc, 0.f), r7 = fmaxf(h4b.w + a7 * sc, 0.f);
    *(uint4*)(hrow + node_loc * 136 + t * 8) =
        make_uint4(pack2(r0, r1), pack2(r2, r3), pack2(r4, r5), pack2(r6, r7));
    __syncthreads();

    // dense: D[16 x MOUT] = H[16x128] @ {Ws|Wn}, fp32 acc
    int l = tid & 63, w = tid >> 6;
    int mloc = l & 15, quad = l >> 4;
    constexpr int NTPW = MOUT / 64;          // n-tiles per wave
    f4v accS[NTPW], accN[NTPW];
#pragma unroll
    for (int nt = 0; nt < NTPW; ++nt) { accS[nt] = (f4v){0,0,0,0}; accN[nt] = (f4v){0,0,0,0}; }
#pragma unroll
    for (int ks = 0; ks < 4; ++ks) {
        int kb = ks * 32 + quad * 8;
        s8v a = *(const s8v*)(hrow + mloc * 136 + kb);
#pragma unroll
        for (int nt = 0; nt < NTPW; ++nt) {
            int n = (w * NTPW + nt) * 16 + mloc;
            s8v bs = *(const s8v*)(wsT + n * 128 + kb);
            s8v bn = *(const s8v*)(wnT + n * 128 + kb);
            accS[nt] = __builtin_amdgcn_mfma_f32_16x16x32_bf16(a, bs, accS[nt], 0, 0, 0);
            accN[nt] = __builtin_amdgcn_mfma_f32_16x16x32_bf16(a, bn, accN[nt], 0, 0, 0);
        }
    }
#pragma unroll
    for (int nt = 0; nt < NTPW; ++nt) {
        int col = (w * NTPW + nt) * 16 + mloc;
        float bv = bias[col];
#pragma unroll
        for (int r = 0; r < 4; ++r) {
            int row = blockIdx.x * 16 + quad * 4 + r;   // always < NN
            hs_out[(size_t)row * MOUT + col] = accS[nt][r] + bv;
            hn_out[(size_t)row * MOUT + col] = f2bf(accN[nt][r]);
        }
    }
}

// ---------------- P5: final aggregate (M=64) -> d_out ----------------

__global__ void agg_out_k(const float* __restrict__ hs_in, const ushort* __restrict__ hn_in,
                          const int* __restrict__ offs, const int* __restrict__ ssrc,
                          float* __restrict__ out) {
    int tid = threadIdx.x;
    int node = blockIdx.x * 32 + (tid >> 3);
    int t = tid & 7;
    if (node >= NN) return;
    int beg = offs[node], end = offs[node + 1];
    const uint4* hn4 = (const uint4*)hn_in;
    float a0 = 0, a1 = 0, a2 = 0, a3 = 0, a4 = 0, a5 = 0, a6 = 0, a7 = 0;
    int e = beg;
    for (; e + 4 <= end; e += 4) {
        int s0 = ssrc[e], s1 = ssrc[e + 1], s2 = ssrc[e + 2], s3 = ssrc[e + 3];
        uint4 v0 = hn4[(size_t)s0 * 8 + t];
        uint4 v1 = hn4[(size_t)s1 * 8 + t];
        uint4 v2 = hn4[(size_t)s2 * 8 + t];
        uint4 v3 = hn4[(size_t)s3 * 8 + t];
        a0 += bf_lo(v0.x) + bf_lo(v1.x) + bf_lo(v2.x) + bf_lo(v3.x);
        a1 += bf_hi(v0.x) + bf_hi(v1.x) + bf_hi(v2.x) + bf_hi(v3.x);
        a2 += bf_lo(v0.y) + bf_lo(v1.y) + bf_lo(v2.y) + bf_lo(v3.y);
        a3 += bf_hi(v0.y) + bf_hi(v1.y) + bf_hi(v2.y) + bf_hi(v3.y);
        a4 += bf_lo(v0.z) + bf_lo(v1.z) + bf_lo(v2.z) + bf_lo(v3.z);
        a5 += bf_hi(v0.z) + bf_hi(v1.z) + bf_hi(v2.z) + bf_hi(v3.z);
        a6 += bf_lo(v0.w) + bf_lo(v1.w) + bf_lo(v2.w) + bf_lo(v3.w);
        a7 += bf_hi(v0.w) + bf_hi(v1.w) + bf_hi(v2.w) + bf_hi(v3.w);
    }
    for (; e < end; ++e) {
        uint4 v = hn4[(size_t)ssrc[e] * 8 + t];
        a0 += bf_lo(v.x); a1 += bf_hi(v.x); a2 += bf_lo(v.y); a3 += bf_hi(v.y);
        a4 += bf_lo(v.z); a5 += bf_hi(v.z); a6 += bf_lo(v.w); a7 += bf_hi(v.w);
    }
    int deg = end - beg;
    float sc = 1.0f / (float)(deg > 0 ? deg : 1);
    float4 h4a = ((const float4*)hs_in)[(size_t)node * 16 + 2 * t];
    float4 h4b = ((const float4*)hs_in)[(size_t)node * 16 + 2 * t + 1];
    ((float4*)out)[(size_t)node * 16 + 2 * t] =
        make_float4(h4a.x + a0 * sc, h4a.y + a1 * sc, h4a.z + a2 * sc, h4a.w + a3 * sc);
    ((float4*)out)[(size_t)node * 16 + 2 * t + 1] =
        make_float4(h4b.x + a4 * sc, h4b.y + a5 * sc, h4b.z + a6 * sc, h4b.w + a7 * sc);
}

// ---------------- launch ----------------

extern "C" void kernel_launch(void* const* d_in, const int* in_sizes, int n_in,
                              void* d_out, int out_size, void* d_ws, size_t ws_size,
                              hipStream_t stream) {
    const float* x   = (const float*)d_in[0];
    const float* Ws0 = (const float*)d_in[1];
    const float* Wn0 = (const float*)d_in[2];
    const float* b0  = (const float*)d_in[3];
    const float* Ws1 = (const float*)d_in[4];
    const float* Wn1 = (const float*)d_in[5];
    const float* b1  = (const float*)d_in[6];
    const float* Ws2 = (const float*)d_in[7];
    const float* Wn2 = (const float*)d_in[8];
    const float* b2  = (const float*)d_in[9];
    const int* esrc  = (const int*)d_in[10];
    const int* edst  = (const int*)d_in[11];
    float* out = (float*)d_out;

    // workspace layout (16B-aligned users first), same as R4
    float*  hsA = (float*)d_ws;                        // NN*128 f32
    float*  hsB = hsA + (size_t)NN * 128;              // NN*128 f32
    ushort* hnA = (ushort*)(hsB + (size_t)NN * 128);   // NN*128 bf16
    ushort* hnB = hnA + (size_t)NN * 128;              // NN*128 bf16
    ushort* xb  = hnB + (size_t)NN * 128;              // NN*128 bf16
    ushort* wt  = xb + (size_t)NN * 128;               // 81920 bf16 (W^T x6)
    unsigned* tmp = (unsigned*)(wt + 81920);           // NE packed edges
    int* ssrc = (int*)(tmp + NE);                      // NE
    int* offs = ssrc + NE;                             // NN+1
    int* blockhist = offs + NN + 1;                    // NBLKA*NBINS
    int* binstart = blockhist + NBLKA * NBINS;         // NBINS+1

    prep_k<<<NBLKA + 64 + 6, 256, 0, stream>>>(edst, blockhist, x, xb,
                                               Ws0, Wn0, Ws1, Wn1, Ws2, Wn2, wt);
    scatdense_k<<<NBLKA + 313, 256, 0, stream>>>(esrc, edst, blockhist, binstart,
                                                 tmp, xb, wt, b0, hsA, hnA);
    sort_k<<<NBINS, 256, 0, stream>>>(tmp, binstart, offs, ssrc);
    agg_dense_k<128><<<NN / 16, 256, 0, stream>>>(hsA, hnA, offs, ssrc,
                                                  wt + 32768, wt + 49152, b1, hsB, hnB);
    agg_dense_k<64><<<NN / 16, 256, 0, stream>>>(hsB, hnB, offs, ssrc,
                                                 wt + 65536, wt + 73728, b2, hsA, hnA);
    agg_out_k<<<(NN + 31) / 32, 256, 0, stream>>>(hsA, hnA, offs, ssrc, out);
}

// Round 7
// 169.158 us; speedup vs baseline: 3.1718x; 1.0964x over previous
//
#include <hip/hip_runtime.h>

// GraphSAGE 3-layer, N=10000, E=640000, D=128->128->64, MI355X.
// R7: reservation-based CSR build. Scatter blocks LDS-hist their 2560 edges,
// reserve a run in each bin's FIXED padded region (CAP=3072, mean 2045, +23
// sigma) via one global atomicAdd per (block,bin), then scatter. Deletes: the
// 250-iteration blockhist scan per scatter block, the Hillis-Steele, the
// blockhist array, prep's hist role, and sort's binstart scan (binstart ==
// bin*CAP). Aggs read explicit offs[]/ends[] and unroll gathers 4->8 (gathers
// are L2-latency-bound; double MLP).
//  P0 prep: x->bf16, W->W^T bf16 (LDS transpose), zero bincnt  [71 blocks]
//  P1 scatter (hist+reserve+scatter) + MFMA dense0             [250+313]
//  P2 per-bin fine sort -> padded ssrc + offs/ends             [313]
//  P3 agg L0 + relu + MFMA dense1 (LDS-fused)                  [625]
//  P4 agg L1 + relu + MFMA dense2 (LDS-fused)                  [625]
//  P5 agg L2 -> d_out                                          [313]
// Aggregation is post-matmul (linearity of mean agg). Neighbor tables bf16,
// fp32 accumulate everywhere; self path hs stays fp32.
// MFMA layouts (verified R4): A[m=lane&15][k=quad*8+j], B[n=lane&15][k=quad*8+j]
// (A*B^T with W^T staged), C/D col=lane&15, row=quad*4+reg.

#define NN 10000
#define NE 640000
#define NBINS 313      // coarse bin = dst >> 5
#define NBLKA 250
#define CHUNK 2560     // 250*2560 == NE
#define CAP 3072       // padded per-bin region (mean 2045, sigma ~45)
#define SORT_CAP 4096

typedef __attribute__((ext_vector_type(8))) short s8v;   // 8 bf16 (4 VGPRs)
typedef __attribute__((ext_vector_type(4))) float f4v;   // MFMA C/D

__device__ __forceinline__ ushort f2bf(float f) {        // RNE f32->bf16
    unsigned u = __float_as_uint(f);
    return (ushort)((u + 0x7FFFu + ((u >> 16) & 1u)) >> 16);
}
__device__ __forceinline__ unsigned pack2(float a, float b) {
    return (unsigned)f2bf(a) | ((unsigned)f2bf(b) << 16);
}
__device__ __forceinline__ float bf_lo(unsigned u) { return __uint_as_float(u << 16); }
__device__ __forceinline__ float bf_hi(unsigned u) { return __uint_as_float(u & 0xFFFF0000u); }

// ---------------- P0: bf16 prep + zero bincnt ----------------

__global__ void prep_k(const float* __restrict__ x, ushort* __restrict__ xb,
                       const float* __restrict__ Ws0, const float* __restrict__ Wn0,
                       const float* __restrict__ Ws1, const float* __restrict__ Wn1,
                       const float* __restrict__ Ws2, const float* __restrict__ Wn2,
                       ushort* __restrict__ wt, int* __restrict__ bincnt) {
    __shared__ ushort ps[128 * 128];         // 32KB transpose tile
    int blk = blockIdx.x, tid = threadIdx.x;
    if (blk < 64) {                          // x -> bf16 (320000 float4 total)
        const float4* xv = (const float4*)x;
        uint2* xo = (uint2*)xb;
        for (int i = tid; i < 5000; i += 256) {
            int idx = blk * 5000 + i;
            float4 v = xv[idx];
            xo[idx] = make_uint2(pack2(v.x, v.y), pack2(v.z, v.w));
        }
    } else if (blk < 70) {                   // 6 weight transposes -> W^T bf16
        int m = blk - 64;                    // 0..5
        const float* W = (m == 0) ? Ws0 : (m == 1) ? Wn0 : (m == 2) ? Ws1
                       : (m == 3) ? Wn1 : (m == 4) ? Ws2 : Wn2;
        int MC = (m < 4) ? 128 : 64;
        ushort* dst = wt + ((m < 4) ? m * 16384 : 65536 + (m - 4) * 8192);
        int tot = 128 * MC;
        for (int idx = tid; idx < tot; idx += 256) {     // coalesced read
            int k = (MC == 128) ? (idx >> 7) : (idx >> 6);
            int n = (MC == 128) ? (idx & 127) : (idx & 63);
            ps[n * 128 + k] = f2bf(W[idx]);              // LDS transpose
        }
        __syncthreads();
        for (int idx = tid; idx < tot; idx += 256)       // coalesced write
            dst[idx] = ps[idx];
    } else {                                 // zero the bin cursors
        for (int i = tid; i < NBINS; i += 256) bincnt[i] = 0;
    }
}

// ---------------- P1: scatter (hist + reserve + scatter) + MFMA dense0 ------

__device__ void scatter_body(const int* __restrict__ src, const int* __restrict__ dst,
                             int* __restrict__ bincnt, unsigned* __restrict__ tmp2,
                             int blk, int* smem) {
    int* h = smem;                           // NBINS block-local counts
    int* cur = smem + NBINS;                 // NBINS absolute cursors
    int tid = threadIdx.x;
    for (int i = tid; i < NBINS; i += 256) h[i] = 0;
    __syncthreads();
    int base = blk * CHUNK;
    for (int i = tid; i < CHUNK; i += 256)   // pass 1: count
        atomicAdd(&h[dst[base + i] >> 5], 1);
    __syncthreads();
    for (int bin = tid; bin < NBINS; bin += 256) {       // reserve runs
        int c = h[bin];
        int off = c ? atomicAdd(&bincnt[bin], c) : 0;
        cur[bin] = bin * CAP + off;
    }
    __syncthreads();
    for (int i = tid; i < CHUNK; i += 256) { // pass 2: scatter
        int d = dst[base + i], s = src[base + i];
        int bin = d >> 5;
        int pos = atomicAdd(&cur[bin], 1);
        if (pos < bin * CAP + CAP)           // overflow guard (never expected)
            tmp2[pos] = ((unsigned)s << 5) | (unsigned)(d & 31);
    }
}

__device__ void dense0_body(const ushort* __restrict__ xb, const ushort* __restrict__ wt,
                            const float* __restrict__ b0,
                            float* __restrict__ hs, ushort* __restrict__ hn, int dblk) {
    int l = threadIdx.x & 63, w = threadIdx.x >> 6;
    int mloc = l & 15, quad = l >> 4;
    int row_base = dblk * 32 + (w & 1) * 16;
    int colh = w >> 1;
    int arow = row_base + mloc;
    int arow_c = (arow < NN) ? arow : (NN - 1);
    const ushort* wsT = wt;                  // Ws0^T
    const ushort* wnT = wt + 16384;          // Wn0^T
    f4v accS[4], accN[4];
#pragma unroll
    for (int nt = 0; nt < 4; ++nt) { accS[nt] = (f4v){0,0,0,0}; accN[nt] = (f4v){0,0,0,0}; }
#pragma unroll
    for (int ks = 0; ks < 4; ++ks) {
        int kb = ks * 32 + quad * 8;
        s8v a = *(const s8v*)(xb + (size_t)arow_c * 128 + kb);
#pragma unroll
        for (int nt = 0; nt < 4; ++nt) {
            int n = colh * 64 + nt * 16 + mloc;
            s8v bs = *(const s8v*)(wsT + n * 128 + kb);
            s8v bn = *(const s8v*)(wnT + n * 128 + kb);
            accS[nt] = __builtin_amdgcn_mfma_f32_16x16x32_bf16(a, bs, accS[nt], 0, 0, 0);
            accN[nt] = __builtin_amdgcn_mfma_f32_16x16x32_bf16(a, bn, accN[nt], 0, 0, 0);
        }
    }
#pragma unroll
    for (int nt = 0; nt < 4; ++nt) {
        int col = colh * 64 + nt * 16 + mloc;
        float bv = b0[col];
#pragma unroll
        for (int r = 0; r < 4; ++r) {
            int row = row_base + quad * 4 + r;
            if (row < NN) {
                hs[(size_t)row * 128 + col] = accS[nt][r] + bv;
                hn[(size_t)row * 128 + col] = f2bf(accN[nt][r]);
            }
        }
    }
}

__global__ void scatdense_k(const int* __restrict__ esrc, const int* __restrict__ edst,
                            int* __restrict__ bincnt, unsigned* __restrict__ tmp2,
                            const ushort* __restrict__ xb, const ushort* __restrict__ wt,
                            const float* __restrict__ b0,
                            float* __restrict__ hs, ushort* __restrict__ hn) {
    __shared__ int smem[2 * NBINS];
    int blk = blockIdx.x;
    if (blk < NBLKA)
        scatter_body(esrc, edst, bincnt, tmp2, blk, smem);
    else
        dense0_body(xb, wt, b0, hs, hn, blk - NBLKA);
}

// ---------------- P2: per-bin fine sort -> padded ssrc + offs/ends ----------

__global__ void sort_k(const unsigned* __restrict__ tmp2, const int* __restrict__ bincnt,
                       int* __restrict__ offs, int* __restrict__ ends,
                       int* __restrict__ ssrc) {
    __shared__ int stage[SORT_CAP];
    __shared__ int cnt32[32];
    __shared__ int cur32[32];
    int b = blockIdx.x, tid = threadIdx.x;
    int beg = b * CAP;
    int cnt = bincnt[b];
    if (cnt > CAP) cnt = CAP;
    if (tid < 32) cnt32[tid] = 0;
    __syncthreads();
    for (int i = tid; i < cnt; i += 256)
        atomicAdd(&cnt32[tmp2[beg + i] & 31], 1);
    __syncthreads();
    if (tid == 0) {
        int run = 0;
        for (int i = 0; i < 32; ++i) {
            int node = b * 32 + i;
            if (node < NN) { offs[node] = beg + run; ends[node] = beg + run + cnt32[i]; }
            cur32[i] = run;
            run += cnt32[i];
        }
    }
    __syncthreads();
    for (int i = tid; i < cnt; i += 256) {
        unsigned q = tmp2[beg + i];
        int pos = atomicAdd(&cur32[q & 31], 1);
        stage[pos] = (int)(q >> 5);
    }
    __syncthreads();
    for (int i = tid; i < cnt; i += 256)     // coalesced stream-out
        ssrc[beg + i] = stage[i];
}

// ---------------- P3/P4: agg + relu + fused MFMA dense ----------------
// Block = 16 nodes (625*16 == NN exactly). Gather (unroll 8) -> LDS -> MFMA.

template <int MOUT>
__global__ void agg_dense_k(const float* __restrict__ hs_in, const ushort* __restrict__ hn_in,
                            const int* __restrict__ offs, const int* __restrict__ ends,
                            const int* __restrict__ ssrc,
                            const ushort* __restrict__ wsT, const ushort* __restrict__ wnT,
                            const float* __restrict__ bias,
                            float* __restrict__ hs_out, ushort* __restrict__ hn_out) {
    __shared__ ushort hrow[16 * 136];        // pad 128->136 vs LDS banks
    int tid = threadIdx.x;
    int node_loc = tid >> 4, t = tid & 15;
    int node = blockIdx.x * 16 + node_loc;
    int beg = offs[node], end = ends[node];
    const uint4* hn4 = (const uint4*)hn_in;
    float a0 = 0, a1 = 0, a2 = 0, a3 = 0, a4 = 0, a5 = 0, a6 = 0, a7 = 0;
    int e = beg;
    for (; e + 8 <= end; e += 8) {           // 8-deep MLP (L2-latency-bound)
        int s0 = ssrc[e], s1 = ssrc[e + 1], s2 = ssrc[e + 2], s3 = ssrc[e + 3];
        int s4 = ssrc[e + 4], s5 = ssrc[e + 5], s6 = ssrc[e + 6], s7 = ssrc[e + 7];
        uint4 v0 = hn4[(size_t)s0 * 16 + t];
        uint4 v1 = hn4[(size_t)s1 * 16 + t];
        uint4 v2 = hn4[(size_t)s2 * 16 + t];
        uint4 v3 = hn4[(size_t)s3 * 16 + t];
        uint4 v4 = hn4[(size_t)s4 * 16 + t];
        uint4 v5 = hn4[(size_t)s5 * 16 + t];
        uint4 v6 = hn4[(size_t)s6 * 16 + t];
        uint4 v7 = hn4[(size_t)s7 * 16 + t];
        a0 += bf_lo(v0.x) + bf_lo(v1.x) + bf_lo(v2.x) + bf_lo(v3.x)
            + bf_lo(v4.x) + bf_lo(v5.x) + bf_lo(v6.x) + bf_lo(v7.x);
        a1 += bf_hi(v0.x) + bf_hi(v1.x) + bf_hi(v2.x) + bf_hi(v3.x)
            + bf_hi(v4.x) + bf_hi(v5.x) + bf_hi(v6.x) + bf_hi(v7.x);
        a2 += bf_lo(v0.y) + bf_lo(v1.y) + bf_lo(v2.y) + bf_lo(v3.y)
            + bf_lo(v4.y) + bf_lo(v5.y) + bf_lo(v6.y) + bf_lo(v7.y);
        a3 += bf_hi(v0.y) + bf_hi(v1.y) + bf_hi(v2.y) + bf_hi(v3.y)
            + bf_hi(v4.y) + bf_hi(v5.y) + bf_hi(v6.y) + bf_hi(v7.y);
        a4 += bf_lo(v0.z) + bf_lo(v1.z) + bf_lo(v2.z) + bf_lo(v3.z)
            + bf_lo(v4.z) + bf_lo(v5.z) + bf_lo(v6.z) + bf_lo(v7.z);
        a5 += bf_hi(v0.z) + bf_hi(v1.z) + bf_hi(v2.z) + bf_hi(v3.z)
            + bf_hi(v4.z) + bf_hi(v5.z) + bf_hi(v6.z) + bf_hi(v7.z);
        a6 += bf_lo(v0.w) + bf_lo(v1.w) + bf_lo(v2.w) + bf_lo(v3.w)
            + bf_lo(v4.w) + bf_lo(v5.w) + bf_lo(v6.w) + bf_lo(v7.w);
        a7 += bf_hi(v0.w) + bf_hi(v1.w) + bf_hi(v2.w) + bf_hi(v3.w)
            + bf_hi(v4.w) + bf_hi(v5.w) + bf_hi(v6.w) + bf_hi(v7.w);
    }
    for (; e < end; ++e) {
        uint4 v = hn4[(size_t)ssrc[e] * 16 + t];
        a0 += bf_lo(v.x); a1 += bf_hi(v.x); a2 += bf_lo(v.y); a3 += bf_hi(v.y);
        a4 += bf_lo(v.z); a5 += bf_hi(v.z); a6 += bf_lo(v.w); a7 += bf_hi(v.w);
    }
    int deg = end - beg;
    float sc = 1.0f / (float)(deg > 0 ? deg : 1);
    float4 h4a = ((const float4*)hs_in)[(size_t)node * 32 + 2 * t];
    float4 h4b = ((const float4*)hs_in)[(size_t)node * 32 + 2 * t + 1];
    float r0 = fmaxf(h4a.x + a0 * sc, 0.f), r1 = fmaxf(h4a.y + a1 * sc, 0.f);
    float r2 = fmaxf(h4a.z + a2 * sc, 0.f), r3 = fmaxf(h4a.w + a3 * sc, 0.f);
    float r4 = fmaxf(h4b.x + a4 * sc, 0.f), r5 = fmaxf(h4b.y + a5 * sc, 0.f);
    float r6 = fmaxf(h4b.z + a6 * sc, 0.f), r7 = fmaxf(h4b.w + a7 * sc, 0.f);
    *(uint4*)(hrow + node_loc * 136 + t * 8) =
        make_uint4(pack2(r0, r1), pack2(r2, r3), pack2(r4, r5), pack2(r6, r7));
    __syncthreads();

    // dense: D[16 x MOUT] = H[16x128] @ {Ws|Wn}, fp32 acc
    int l = tid & 63, w = tid >> 6;
    int mloc = l & 15, quad = l >> 4;
    constexpr int NTPW = MOUT / 64;          // n-tiles per wave
    f4v accS[NTPW], accN[NTPW];
#pragma unroll
    for (int nt = 0; nt < NTPW; ++nt) { accS[nt] = (f4v){0,0,0,0}; accN[nt] = (f4v){0,0,0,0}; }
#pragma unroll
    for (int ks = 0; ks < 4; ++ks) {
        int kb = ks * 32 + quad * 8;
        s8v a = *(const s8v*)(hrow + mloc * 136 + kb);
#pragma unroll
        for (int nt = 0; nt < NTPW; ++nt) {
            int n = (w * NTPW + nt) * 16 + mloc;
            s8v bs = *(const s8v*)(wsT + n * 128 + kb);
            s8v bn = *(const s8v*)(wnT + n * 128 + kb);
            accS[nt] = __builtin_amdgcn_mfma_f32_16x16x32_bf16(a, bs, accS[nt], 0, 0, 0);
            accN[nt] = __builtin_amdgcn_mfma_f32_16x16x32_bf16(a, bn, accN[nt], 0, 0, 0);
        }
    }
#pragma unroll
    for (int nt = 0; nt < NTPW; ++nt) {
        int col = (w * NTPW + nt) * 16 + mloc;
        float bv = bias[col];
#pragma unroll
        for (int r = 0; r < 4; ++r) {
            int row = blockIdx.x * 16 + quad * 4 + r;   // always < NN
            hs_out[(size_t)row * MOUT + col] = accS[nt][r] + bv;
            hn_out[(size_t)row * MOUT + col] = f2bf(accN[nt][r]);
        }
    }
}

// ---------------- P5: final aggregate (M=64) -> d_out ----------------

__global__ void agg_out_k(const float* __restrict__ hs_in, const ushort* __restrict__ hn_in,
                          const int* __restrict__ offs, const int* __restrict__ ends,
                          const int* __restrict__ ssrc, float* __restrict__ out) {
    int tid = threadIdx.x;
    int node = blockIdx.x * 32 + (tid >> 3);
    int t = tid & 7;
    if (node >= NN) return;
    int beg = offs[node], end = ends[node];
    const uint4* hn4 = (const uint4*)hn_in;
    float a0 = 0, a1 = 0, a2 = 0, a3 = 0, a4 = 0, a5 = 0, a6 = 0, a7 = 0;
    int e = beg;
    for (; e + 8 <= end; e += 8) {
        int s0 = ssrc[e], s1 = ssrc[e + 1], s2 = ssrc[e + 2], s3 = ssrc[e + 3];
        int s4 = ssrc[e + 4], s5 = ssrc[e + 5], s6 = ssrc[e + 6], s7 = ssrc[e + 7];
        uint4 v0 = hn4[(size_t)s0 * 8 + t];
        uint4 v1 = hn4[(size_t)s1 * 8 + t];
        uint4 v2 = hn4[(size_t)s2 * 8 + t];
        uint4 v3 = hn4[(size_t)s3 * 8 + t];
        uint4 v4 = hn4[(size_t)s4 * 8 + t];
        uint4 v5 = hn4[(size_t)s5 * 8 + t];
        uint4 v6 = hn4[(size_t)s6 * 8 + t];
        uint4 v7 = hn4[(size_t)s7 * 8 + t];
        a0 += bf_lo(v0.x) + bf_lo(v1.x) + bf_lo(v2.x) + bf_lo(v3.x)
            + bf_lo(v4.x) + bf_lo(v5.x) + bf_lo(v6.x) + bf_lo(v7.x);
        a1 += bf_hi(v0.x) + bf_hi(v1.x) + bf_hi(v2.x) + bf_hi(v3.x)
            + bf_hi(v4.x) + bf_hi(v5.x) + bf_hi(v6.x) + bf_hi(v7.x);
        a2 += bf_lo(v0.y) + bf_lo(v1.y) + bf_lo(v2.y) + bf_lo(v3.y)
            + bf_lo(v4.y) + bf_lo(v5.y) + bf_lo(v6.y) + bf_lo(v7.y);
        a3 += bf_hi(v0.y) + bf_hi(v1.y) + bf_hi(v2.y) + bf_hi(v3.y)
            + bf_hi(v4.y) + bf_hi(v5.y) + bf_hi(v6.y) + bf_hi(v7.y);
        a4 += bf_lo(v0.z) + bf_lo(v1.z) + bf_lo(v2.z) + bf_lo(v3.z)
            + bf_lo(v4.z) + bf_lo(v5.z) + bf_lo(v6.z) + bf_lo(v7.z);
        a5 += bf_hi(v0.z) + bf_hi(v1.z) + bf_hi(v2.z) + bf_hi(v3.z)
            + bf_hi(v4.z) + bf_hi(v5.z) + bf_hi(v6.z) + bf_hi(v7.z);
        a6 += bf_lo(v0.w) + bf_lo(v1.w) + bf_lo(v2.w) + bf_lo(v3.w)
            + bf_lo(v4.w) + bf_lo(v5.w) + bf_lo(v6.w) + bf_lo(v7.w);
        a7 += bf_hi(v0.w) + bf_hi(v1.w) + bf_hi(v2.w) + bf_hi(v3.w)
            + bf_hi(v4.w) + bf_hi(v5.w) + bf_hi(v6.w) + bf_hi(v7.w);
    }
    for (; e < end; ++e) {
        uint4 v = hn4[(size_t)ssrc[e] * 8 + t];
        a0 += bf_lo(v.x); a1 += bf_hi(v.x); a2 += bf_lo(v.y); a3 += bf_hi(v.y);
        a4 += bf_lo(v.z); a5 += bf_hi(v.z); a6 += bf_lo(v.w); a7 += bf_hi(v.w);
    }
    int deg = end - beg;
    float sc = 1.0f / (float)(deg > 0 ? deg : 1);
    float4 h4a = ((const float4*)hs_in)[(size_t)node * 16 + 2 * t];
    float4 h4b = ((const float4*)hs_in)[(size_t)node * 16 + 2 * t + 1];
    ((float4*)out)[(size_t)node * 16 + 2 * t] =
        make_float4(h4a.x + a0 * sc, h4a.y + a1 * sc, h4a.z + a2 * sc, h4a.w + a3 * sc);
    ((float4*)out)[(size_t)node * 16 + 2 * t + 1] =
        make_float4(h4b.x + a4 * sc, h4b.y + a5 * sc, h4b.z + a6 * sc, h4b.w + a7 * sc);
}

// ---------------- launch ----------------

extern "C" void kernel_launch(void* const* d_in, const int* in_sizes, int n_in,
                              void* d_out, int out_size, void* d_ws, size_t ws_size,
                              hipStream_t stream) {
    const float* x   = (const float*)d_in[0];
    const float* Ws0 = (const float*)d_in[1];
    const float* Wn0 = (const float*)d_in[2];
    const float* b0  = (const float*)d_in[3];
    const float* Ws1 = (const float*)d_in[4];
    const float* Wn1 = (const float*)d_in[5];
    const float* b1  = (const float*)d_in[6];
    const float* Ws2 = (const float*)d_in[7];
    const float* Wn2 = (const float*)d_in[8];
    const float* b2  = (const float*)d_in[9];
    const int* esrc  = (const int*)d_in[10];
    const int* edst  = (const int*)d_in[11];
    float* out = (float*)d_out;

    // workspace layout (16B-aligned users first)
    float*  hsA = (float*)d_ws;                        // NN*128 f32
    float*  hsB = hsA + (size_t)NN * 128;              // NN*128 f32
    ushort* hnA = (ushort*)(hsB + (size_t)NN * 128);   // NN*128 bf16
    ushort* hnB = hnA + (size_t)NN * 128;              // NN*128 bf16
    ushort* xb  = hnB + (size_t)NN * 128;              // NN*128 bf16
    ushort* wt  = xb + (size_t)NN * 128;               // 81920 bf16 (W^T x6)
    unsigned* tmp2 = (unsigned*)(wt + 81920);          // NBINS*CAP packed edges
    int* ssrc = (int*)(tmp2 + (size_t)NBINS * CAP);    // NBINS*CAP (padded)
    int* offs = ssrc + (size_t)NBINS * CAP;            // NN
    int* ends = offs + NN;                             // NN
    int* bincnt = ends + NN;                           // NBINS

    prep_k<<<71, 256, 0, stream>>>(x, xb, Ws0, Wn0, Ws1, Wn1, Ws2, Wn2, wt, bincnt);
    scatdense_k<<<NBLKA + 313, 256, 0, stream>>>(esrc, edst, bincnt, tmp2,
                                                 xb, wt, b0, hsA, hnA);
    sort_k<<<NBINS, 256, 0, stream>>>(tmp2, bincnt, offs, ends, ssrc);
    agg_dense_k<128><<<NN / 16, 256, 0, stream>>>(hsA, hnA, offs, ends, ssrc,
                                                  wt + 32768, wt + 49152, b1, hsB, hnB);
    agg_dense_k<64><<<NN / 16, 256, 0, stream>>>(hsB, hnB, offs, ends, ssrc,
                                                 wt + 65536, wt + 73728, b2, hsA, hnA);
    agg_out_k<<<(NN + 31) / 32, 256, 0, stream>>>(hsA, hnA, offs, ends, ssrc, out);
}

// Round 9
// 167.172 us; speedup vs baseline: 3.2095x; 1.0119x over previous
//
#include <hip/hip_runtime.h>

// GraphSAGE 3-layer, N=10000, E=640000, D=128->128->64, MI355X.
// R8b (R8 with const-ness compile fix; from R7 @169us; harness floor ~145us):
//  - dense0 reads x fp32 directly and packs bf16 in-register (same RNE
//    rounding => bit-identical); deletes the 7.5MB x->bf16 prep pass.
//  - scatter caches packed edges in LDS on the count pass; scatter pass
//    replays from LDS in identical order (edge list read once, not twice).
//  - wt1/wt2 transposes moved into the scatdense dispatch (first use is P3).
//  P0 prep: Ws0/Wn0 -> W^T bf16 (LDS transpose), zero bincnt   [2 blocks]
//  P1 scatter(250) + MFMA dense0(313) + wt1/wt2 transpose(4)   [567]
//  P2 per-bin fine sort -> padded ssrc + offs/ends             [313]
//  P3 agg L0 + relu + MFMA dense1 (LDS-fused)                  [625]
//  P4 agg L1 + relu + MFMA dense2 (LDS-fused)                  [625]
//  P5 agg L2 -> d_out                                          [313]
// Aggregation is post-matmul (linearity of mean agg). Neighbor tables bf16,
// fp32 accumulate everywhere; self path hs stays fp32.
// MFMA layouts (verified R4): A[m=lane&15][k=quad*8+j], B[n=lane&15][k=quad*8+j]
// (A*B^T with W^T staged), C/D col=lane&15, row=quad*4+reg.

#define NN 10000
#define NE 640000
#define NBINS 313      // coarse bin = dst >> 5
#define NBLKA 250
#define CHUNK 2560     // 250*2560 == NE
#define CAP 3072       // padded per-bin region (mean 2045, sigma ~45)
#define SORT_CAP 4096

typedef __attribute__((ext_vector_type(8))) short s8v;   // 8 bf16 (4 VGPRs)
typedef __attribute__((ext_vector_type(4))) float f4v;   // MFMA C/D

__device__ __forceinline__ ushort f2bf(float f) {        // RNE f32->bf16
    unsigned u = __float_as_uint(f);
    return (ushort)((u + 0x7FFFu + ((u >> 16) & 1u)) >> 16);
}
__device__ __forceinline__ unsigned pack2(float a, float b) {
    return (unsigned)f2bf(a) | ((unsigned)f2bf(b) << 16);
}
__device__ __forceinline__ float bf_lo(unsigned u) { return __uint_as_float(u << 16); }
__device__ __forceinline__ float bf_hi(unsigned u) { return __uint_as_float(u & 0xFFFF0000u); }

// shared transpose body: W[128 x MC] fp32 -> W^T[MC x 128] bf16
__device__ void wtrans_body(const float* __restrict__ W, ushort* __restrict__ dst,
                            int MC, ushort* ps) {
    int tid = threadIdx.x;
    int tot = 128 * MC;
    for (int idx = tid; idx < tot; idx += 256) {         // coalesced read
        int k = (MC == 128) ? (idx >> 7) : (idx >> 6);
        int n = (MC == 128) ? (idx & 127) : (idx & 63);
        ps[n * 128 + k] = f2bf(W[idx]);                  // LDS transpose
    }
    __syncthreads();
    for (int idx = tid; idx < tot; idx += 256)           // coalesced write
        dst[idx] = ps[idx];
}

// ---------------- P0: Ws0/Wn0 transpose + zero bincnt ----------------

__global__ void prep_k(const float* __restrict__ Ws0, const float* __restrict__ Wn0,
                       ushort* __restrict__ wt, int* __restrict__ bincnt) {
    __shared__ ushort ps[128 * 128];         // 32KB transpose tile
    int blk = blockIdx.x, tid = threadIdx.x;
    if (blk == 0) {
        for (int i = tid; i < NBINS; i += 256) bincnt[i] = 0;
        wtrans_body(Ws0, wt, 128, ps);
    } else {
        wtrans_body(Wn0, wt + 16384, 128, ps);
    }
}

// ---------------- P1: scatter (LDS edge cache) + MFMA dense0 + wt1/wt2 ------

__device__ void scatter_body(const int* __restrict__ src, const int* __restrict__ dst,
                             int* __restrict__ bincnt, unsigned* __restrict__ tmp2,
                             int blk, int* smem) {
    int* h = smem;                           // NBINS block-local counts
    int* cur = smem + NBINS;                 // NBINS absolute cursors
    unsigned* ec = (unsigned*)(smem + 2 * NBINS);   // CHUNK cached edges
    int tid = threadIdx.x;
    for (int i = tid; i < NBINS; i += 256) h[i] = 0;
    __syncthreads();
    int base = blk * CHUNK;
    for (int i = tid; i < CHUNK; i += 256) { // pass 1: count + cache
        int d = dst[base + i], s = src[base + i];
        int bin = d >> 5;
        ec[i] = ((unsigned)bin << 19) | ((unsigned)s << 5) | (unsigned)(d & 31);
        atomicAdd(&h[bin], 1);
    }
    __syncthreads();
    for (int bin = tid; bin < NBINS; bin += 256) {       // reserve runs
        int c = h[bin];
        int off = c ? atomicAdd(&bincnt[bin], c) : 0;
        cur[bin] = bin * CAP + off;
    }
    __syncthreads();
    for (int i = tid; i < CHUNK; i += 256) { // pass 2: scatter from LDS
        unsigned word = ec[i];
        int bin = (int)(word >> 19);
        int pos = atomicAdd(&cur[bin], 1);
        if (pos < bin * CAP + CAP)           // overflow guard (never expected)
            tmp2[pos] = word & 0x7FFFFu;     // src:14b | dstloc:5b
    }
}

__device__ void dense0_body(const float* __restrict__ x, const ushort* __restrict__ wt,
                            const float* __restrict__ b0,
                            float* __restrict__ hs, ushort* __restrict__ hn, int dblk) {
    int l = threadIdx.x & 63, w = threadIdx.x >> 6;
    int mloc = l & 15, quad = l >> 4;
    int row_base = dblk * 32 + (w & 1) * 16;
    int colh = w >> 1;
    int arow = row_base + mloc;
    int arow_c = (arow < NN) ? arow : (NN - 1);
    const float4* xrow = (const float4*)(x + (size_t)arow_c * 128);
    const ushort* wsT = wt;                  // Ws0^T
    const ushort* wnT = wt + 16384;          // Wn0^T
    f4v accS[4], accN[4];
#pragma unroll
    for (int nt = 0; nt < 4; ++nt) { accS[nt] = (f4v){0,0,0,0}; accN[nt] = (f4v){0,0,0,0}; }
#pragma unroll
    for (int ks = 0; ks < 4; ++ks) {
        int kb = ks * 32 + quad * 8;
        float4 f0 = xrow[kb >> 2];           // x fp32, packed to bf16 in-reg
        float4 f1 = xrow[(kb >> 2) + 1];     // (same RNE as the old prep pass)
        s8v a;
        a[0] = (short)f2bf(f0.x); a[1] = (short)f2bf(f0.y);
        a[2] = (short)f2bf(f0.z); a[3] = (short)f2bf(f0.w);
        a[4] = (short)f2bf(f1.x); a[5] = (short)f2bf(f1.y);
        a[6] = (short)f2bf(f1.z); a[7] = (short)f2bf(f1.w);
#pragma unroll
        for (int nt = 0; nt < 4; ++nt) {
            int n = colh * 64 + nt * 16 + mloc;
            s8v bs = *(const s8v*)(wsT + n * 128 + kb);
            s8v bn = *(const s8v*)(wnT + n * 128 + kb);
            accS[nt] = __builtin_amdgcn_mfma_f32_16x16x32_bf16(a, bs, accS[nt], 0, 0, 0);
            accN[nt] = __builtin_amdgcn_mfma_f32_16x16x32_bf16(a, bn, accN[nt], 0, 0, 0);
        }
    }
#pragma unroll
    for (int nt = 0; nt < 4; ++nt) {
        int col = colh * 64 + nt * 16 + mloc;
        float bv = b0[col];
#pragma unroll
        for (int r = 0; r < 4; ++r) {
            int row = row_base + quad * 4 + r;
            if (row < NN) {
                hs[(size_t)row * 128 + col] = accS[nt][r] + bv;
                hn[(size_t)row * 128 + col] = f2bf(accN[nt][r]);
            }
        }
    }
}

__global__ void scatdense_k(const int* __restrict__ esrc, const int* __restrict__ edst,
                            int* __restrict__ bincnt, unsigned* __restrict__ tmp2,
                            const float* __restrict__ x, ushort* __restrict__ wt,
                            const float* __restrict__ b0,
                            float* __restrict__ hs, ushort* __restrict__ hn,
                            const float* __restrict__ Ws1, const float* __restrict__ Wn1,
                            const float* __restrict__ Ws2, const float* __restrict__ Wn2) {
    __shared__ ushort ps[128 * 128];         // 32KB union: edge cache / transpose
    int blk = blockIdx.x;
    if (blk < NBLKA) {
        scatter_body(esrc, edst, bincnt, tmp2, blk, (int*)ps);
    } else if (blk < NBLKA + 313) {
        dense0_body(x, wt, b0, hs, hn, blk - NBLKA);
    } else {                                 // wt1/wt2 transposes (used in P3/P4)
        int m = blk - NBLKA - 313;           // 0..3 -> Ws1,Wn1,Ws2,Wn2
        const float* W = (m == 0) ? Ws1 : (m == 1) ? Wn1 : (m == 2) ? Ws2 : Wn2;
        int MC = (m < 2) ? 128 : 64;
        ushort* dst = wt + ((m < 2) ? 32768 + m * 16384 : 65536 + (m - 2) * 8192);
        wtrans_body(W, dst, MC, ps);
    }
}

// ---------------- P2: per-bin fine sort -> padded ssrc + offs/ends ----------

__global__ void sort_k(const unsigned* __restrict__ tmp2, const int* __restrict__ bincnt,
                       int* __restrict__ offs, int* __restrict__ ends,
                       int* __restrict__ ssrc) {
    __shared__ int stage[SORT_CAP];
    __shared__ int cnt32[32];
    __shared__ int cur32[32];
    int b = blockIdx.x, tid = threadIdx.x;
    int beg = b * CAP;
    int cnt = bincnt[b];
    if (cnt > CAP) cnt = CAP;
    if (tid < 32) cnt32[tid] = 0;
    __syncthreads();
    for (int i = tid; i < cnt; i += 256)
        atomicAdd(&cnt32[tmp2[beg + i] & 31], 1);
    __syncthreads();
    if (tid == 0) {
        int run = 0;
        for (int i = 0; i < 32; ++i) {
            int node = b * 32 + i;
            if (node < NN) { offs[node] = beg + run; ends[node] = beg + run + cnt32[i]; }
            cur32[i] = run;
            run += cnt32[i];
        }
    }
    __syncthreads();
    for (int i = tid; i < cnt; i += 256) {
        unsigned q = tmp2[beg + i];
        int pos = atomicAdd(&cur32[q & 31], 1);
        stage[pos] = (int)(q >> 5);
    }
    __syncthreads();
    for (int i = tid; i < cnt; i += 256)     // coalesced stream-out
        ssrc[beg + i] = stage[i];
}

// ---------------- P3/P4: agg + relu + fused MFMA dense ----------------
// Block = 16 nodes (625*16 == NN exactly). Gather (unroll 8) -> LDS -> MFMA.

template <int MOUT>
__global__ void agg_dense_k(const float* __restrict__ hs_in, const ushort* __restrict__ hn_in,
                            const int* __restrict__ offs, const int* __restrict__ ends,
                            const int* __restrict__ ssrc,
                            const ushort* __restrict__ wsT, const ushort* __restrict__ wnT,
                            const float* __restrict__ bias,
                            float* __restrict__ hs_out, ushort* __restrict__ hn_out) {
    __shared__ ushort hrow[16 * 136];        // pad 128->136 vs LDS banks
    int tid = threadIdx.x;
    int node_loc = tid >> 4, t = tid & 15;
    int node = blockIdx.x * 16 + node_loc;
    int beg = offs[node], end = ends[node];
    const uint4* hn4 = (const uint4*)hn_in;
    float a0 = 0, a1 = 0, a2 = 0, a3 = 0, a4 = 0, a5 = 0, a6 = 0, a7 = 0;
    int e = beg;
    for (; e + 8 <= end; e += 8) {           // 8-deep MLP (L2-latency-bound)
        int s0 = ssrc[e], s1 = ssrc[e + 1], s2 = ssrc[e + 2], s3 = ssrc[e + 3];
        int s4 = ssrc[e + 4], s5 = ssrc[e + 5], s6 = ssrc[e + 6], s7 = ssrc[e + 7];
        uint4 v0 = hn4[(size_t)s0 * 16 + t];
        uint4 v1 = hn4[(size_t)s1 * 16 + t];
        uint4 v2 = hn4[(size_t)s2 * 16 + t];
        uint4 v3 = hn4[(size_t)s3 * 16 + t];
        uint4 v4 = hn4[(size_t)s4 * 16 + t];
        uint4 v5 = hn4[(size_t)s5 * 16 + t];
        uint4 v6 = hn4[(size_t)s6 * 16 + t];
        uint4 v7 = hn4[(size_t)s7 * 16 + t];
        a0 += bf_lo(v0.x) + bf_lo(v1.x) + bf_lo(v2.x) + bf_lo(v3.x)
            + bf_lo(v4.x) + bf_lo(v5.x) + bf_lo(v6.x) + bf_lo(v7.x);
        a1 += bf_hi(v0.x) + bf_hi(v1.x) + bf_hi(v2.x) + bf_hi(v3.x)
            + bf_hi(v4.x) + bf_hi(v5.x) + bf_hi(v6.x) + bf_hi(v7.x);
        a2 += bf_lo(v0.y) + bf_lo(v1.y) + bf_lo(v2.y) + bf_lo(v3.y)
            + bf_lo(v4.y) + bf_lo(v5.y) + bf_lo(v6.y) + bf_lo(v7.y);
        a3 += bf_hi(v0.y) + bf_hi(v1.y) + bf_hi(v2.y) + bf_hi(v3.y)
            + bf_hi(v4.y) + bf_hi(v5.y) + bf_hi(v6.y) + bf_hi(v7.y);
        a4 += bf_lo(v0.z) + bf_lo(v1.z) + bf_lo(v2.z) + bf_lo(v3.z)
            + bf_lo(v4.z) + bf_lo(v5.z) + bf_lo(v6.z) + bf_lo(v7.z);
        a5 += bf_hi(v0.z) + bf_hi(v1.z) + bf_hi(v2.z) + bf_hi(v3.z)
            + bf_hi(v4.z) + bf_hi(v5.z) + bf_hi(v6.z) + bf_hi(v7.z);
        a6 += bf_lo(v0.w) + bf_lo(v1.w) + bf_lo(v2.w) + bf_lo(v3.w)
            + bf_lo(v4.w) + bf_lo(v5.w) + bf_lo(v6.w) + bf_lo(v7.w);
        a7 += bf_hi(v0.w) + bf_hi(v1.w) + bf_hi(v2.w) + bf_hi(v3.w)
            + bf_hi(v4.w) + bf_hi(v5.w) + bf_hi(v6.w) + bf_hi(v7.w);
    }
    for (; e < end; ++e) {
        uint4 v = hn4[(size_t)ssrc[e] * 16 + t];
        a0 += bf_lo(v.x); a1 += bf_hi(v.x); a2 += bf_lo(v.y); a3 += bf_hi(v.y);
        a4 += bf_lo(v.z); a5 += bf_hi(v.z); a6 += bf_lo(v.w); a7 += bf_hi(v.w);
    }
    int deg = end - beg;
    float sc = 1.0f / (float)(deg > 0 ? deg : 1);
    float4 h4a = ((const float4*)hs_in)[(size_t)node * 32 + 2 * t];
    float4 h4b = ((const float4*)hs_in)[(size_t)node * 32 + 2 * t + 1];
    float r0 = fmaxf(h4a.x + a0 * sc, 0.f), r1 = fmaxf(h4a.y + a1 * sc, 0.f);
    float r2 = fmaxf(h4a.z + a2 * sc, 0.f), r3 = fmaxf(h4a.w + a3 * sc, 0.f);
    float r4 = fmaxf(h4b.x + a4 * sc, 0.f), r5 = fmaxf(h4b.y + a5 * sc, 0.f);
    float r6 = fmaxf(h4b.z + a6 * sc, 0.f), r7 = fmaxf(h4b.w + a7 * sc, 0.f);
    *(uint4*)(hrow + node_loc * 136 + t * 8) =
        make_uint4(pack2(r0, r1), pack2(r2, r3), pack2(r4, r5), pack2(r6, r7));
    __syncthreads();

    // dense: D[16 x MOUT] = H[16x128] @ {Ws|Wn}, fp32 acc
    int l = tid & 63, w = tid >> 6;
    int mloc = l & 15, quad = l >> 4;
    constexpr int NTPW = MOUT / 64;          // n-tiles per wave
    f4v accS[NTPW], accN[NTPW];
#pragma unroll
    for (int nt = 0; nt < NTPW; ++nt) { accS[nt] = (f4v){0,0,0,0}; accN[nt] = (f4v){0,0,0,0}; }
#pragma unroll
    for (int ks = 0; ks < 4; ++ks) {
        int kb = ks * 32 + quad * 8;
        s8v a = *(const s8v*)(hrow + mloc * 136 + kb);
#pragma unroll
        for (int nt = 0; nt < NTPW; ++nt) {
            int n = (w * NTPW + nt) * 16 + mloc;
            s8v bs = *(const s8v*)(wsT + n * 128 + kb);
            s8v bn = *(const s8v*)(wnT + n * 128 + kb);
            accS[nt] = __builtin_amdgcn_mfma_f32_16x16x32_bf16(a, bs, accS[nt], 0, 0, 0);
            accN[nt] = __builtin_amdgcn_mfma_f32_16x16x32_bf16(a, bn, accN[nt], 0, 0, 0);
        }
    }
#pragma unroll
    for (int nt = 0; nt < NTPW; ++nt) {
        int col = (w * NTPW + nt) * 16 + mloc;
        float bv = bias[col];
#pragma unroll
        for (int r = 0; r < 4; ++r) {
            int row = blockIdx.x * 16 + quad * 4 + r;   // always < NN
            hs_out[(size_t)row * MOUT + col] = accS[nt][r] + bv;
            hn_out[(size_t)row * MOUT + col] = f2bf(accN[nt][r]);
        }
    }
}

// ---------------- P5: final aggregate (M=64) -> d_out ----------------

__global__ void agg_out_k(const float* __restrict__ hs_in, const ushort* __restrict__ hn_in,
                          const int* __restrict__ offs, const int* __restrict__ ends,
                          const int* __restrict__ ssrc, float* __restrict__ out) {
    int tid = threadIdx.x;
    int node = blockIdx.x * 32 + (tid >> 3);
    int t = tid & 7;
    if (node >= NN) return;
    int beg = offs[node], end = ends[node];
    const uint4* hn4 = (const uint4*)hn_in;
    float a0 = 0, a1 = 0, a2 = 0, a3 = 0, a4 = 0, a5 = 0, a6 = 0, a7 = 0;
    int e = beg;
    for (; e + 8 <= end; e += 8) {
        int s0 = ssrc[e], s1 = ssrc[e + 1], s2 = ssrc[e + 2], s3 = ssrc[e + 3];
        int s4 = ssrc[e + 4], s5 = ssrc[e + 5], s6 = ssrc[e + 6], s7 = ssrc[e + 7];
        uint4 v0 = hn4[(size_t)s0 * 8 + t];
        uint4 v1 = hn4[(size_t)s1 * 8 + t];
        uint4 v2 = hn4[(size_t)s2 * 8 + t];
        uint4 v3 = hn4[(size_t)s3 * 8 + t];
        uint4 v4 = hn4[(size_t)s4 * 8 + t];
        uint4 v5 = hn4[(size_t)s5 * 8 + t];
        uint4 v6 = hn4[(size_t)s6 * 8 + t];
        uint4 v7 = hn4[(size_t)s7 * 8 + t];
        a0 += bf_lo(v0.x) + bf_lo(v1.x) + bf_lo(v2.x) + bf_lo(v3.x)
            + bf_lo(v4.x) + bf_lo(v5.x) + bf_lo(v6.x) + bf_lo(v7.x);
        a1 += bf_hi(v0.x) + bf_hi(v1.x) + bf_hi(v2.x) + bf_hi(v3.x)
            + bf_hi(v4.x) + bf_hi(v5.x) + bf_hi(v6.x) + bf_hi(v7.x);
        a2 += bf_lo(v0.y) + bf_lo(v1.y) + bf_lo(v2.y) + bf_lo(v3.y)
            + bf_lo(v4.y) + bf_lo(v5.y) + bf_lo(v6.y) + bf_lo(v7.y);
        a3 += bf_hi(v0.y) + bf_hi(v1.y) + bf_hi(v2.y) + bf_hi(v3.y)
            + bf_hi(v4.y) + bf_hi(v5.y) + bf_hi(v6.y) + bf_hi(v7.y);
        a4 += bf_lo(v0.z) + bf_lo(v1.z) + bf_lo(v2.z) + bf_lo(v3.z)
            + bf_lo(v4.z) + bf_lo(v5.z) + bf_lo(v6.z) + bf_lo(v7.z);
        a5 += bf_hi(v0.z) + bf_hi(v1.z) + bf_hi(v2.z) + bf_hi(v3.z)
            + bf_hi(v4.z) + bf_hi(v5.z) + bf_hi(v6.z) + bf_hi(v7.z);
        a6 += bf_lo(v0.w) + bf_lo(v1.w) + bf_lo(v2.w) + bf_lo(v3.w)
            + bf_lo(v4.w) + bf_lo(v5.w) + bf_lo(v6.w) + bf_lo(v7.w);
        a7 += bf_hi(v0.w) + bf_hi(v1.w) + bf_hi(v2.w) + bf_hi(v3.w)
            + bf_hi(v4.w) + bf_hi(v5.w) + bf_hi(v6.w) + bf_hi(v7.w);
    }
    for (; e < end; ++e) {
        uint4 v = hn4[(size_t)ssrc[e] * 8 + t];
        a0 += bf_lo(v.x); a1 += bf_hi(v.x); a2 += bf_lo(v.y); a3 += bf_hi(v.y);
        a4 += bf_lo(v.z); a5 += bf_hi(v.z); a6 += bf_lo(v.w); a7 += bf_hi(v.w);
    }
    int deg = end - beg;
    float sc = 1.0f / (float)(deg > 0 ? deg : 1);
    float4 h4a = ((const float4*)hs_in)[(size_t)node * 16 + 2 * t];
    float4 h4b = ((const float4*)hs_in)[(size_t)node * 16 + 2 * t + 1];
    ((float4*)out)[(size_t)node * 16 + 2 * t] =
        make_float4(h4a.x + a0 * sc, h4a.y + a1 * sc, h4a.z + a2 * sc, h4a.w + a3 * sc);
    ((float4*)out)[(size_t)node * 16 + 2 * t + 1] =
        make_float4(h4b.x + a4 * sc, h4b.y + a5 * sc, h4b.z + a6 * sc, h4b.w + a7 * sc);
}

// ---------------- launch ----------------

extern "C" void kernel_launch(void* const* d_in, const int* in_sizes, int n_in,
                              void* d_out, int out_size, void* d_ws, size_t ws_size,
                              hipStream_t stream) {
    const float* x   = (const float*)d_in[0];
    const float* Ws0 = (const float*)d_in[1];
    const float* Wn0 = (const float*)d_in[2];
    const float* b0  = (const float*)d_in[3];
    const float* Ws1 = (const float*)d_in[4];
    const float* Wn1 = (const float*)d_in[5];
    const float* b1  = (const float*)d_in[6];
    const float* Ws2 = (const float*)d_in[7];
    const float* Wn2 = (const float*)d_in[8];
    const float* b2  = (const float*)d_in[9];
    const int* esrc  = (const int*)d_in[10];
    const int* edst  = (const int*)d_in[11];
    float* out = (float*)d_out;

    // workspace layout (16B-aligned users first)
    float*  hsA = (float*)d_ws;                        // NN*128 f32
    float*  hsB = hsA + (size_t)NN * 128;              // NN*128 f32
    ushort* hnA = (ushort*)(hsB + (size_t)NN * 128);   // NN*128 bf16
    ushort* hnB = hnA + (size_t)NN * 128;              // NN*128 bf16
    ushort* wt  = hnB + (size_t)NN * 128;              // 81920 bf16 (W^T x6)
    unsigned* tmp2 = (unsigned*)(wt + 81920);          // NBINS*CAP packed edges
    int* ssrc = (int*)(tmp2 + (size_t)NBINS * CAP);    // NBINS*CAP (padded)
    int* offs = ssrc + (size_t)NBINS * CAP;            // NN
    int* ends = offs + NN;                             // NN
    int* bincnt = ends + NN;                           // NBINS

    prep_k<<<2, 256, 0, stream>>>(Ws0, Wn0, wt, bincnt);
    scatdense_k<<<NBLKA + 313 + 4, 256, 0, stream>>>(esrc, edst, bincnt, tmp2,
                                                     x, wt, b0, hsA, hnA,
                                                     Ws1, Wn1, Ws2, Wn2);
    sort_k<<<NBINS, 256, 0, stream>>>(tmp2, bincnt, offs, ends, ssrc);
    agg_dense_k<128><<<NN / 16, 256, 0, stream>>>(hsA, hnA, offs, ends, ssrc,
                                                  wt + 32768, wt + 49152, b1, hsB, hnB);
    agg_dense_k<64><<<NN / 16, 256, 0, stream>>>(hsB, hnB, offs, ends, ssrc,
                                                 wt + 65536, wt + 73728, b2, hsA, hnA);
    agg_out_k<<<(NN + 31) / 32, 256, 0, stream>>>(hsA, hnA, offs, ends, ssrc, out);
}